// Round 14
// baseline (884.123 us; speedup 1.0000x reference)
//
#include <hip/hip_runtime.h>
#include <hip/hip_bf16.h>
#include <math.h>

typedef unsigned short u16;

// Compiler memory fence + drain of this wave's LDS ops. Each task's LDS region
// is touched by exactly ONE wave; same-wave DS ops execute in order.
#define WAVE_SYNC() asm volatile("s_waitcnt lgkmcnt(0)" ::: "memory")

// ---------- dtype helpers ----------
__device__ __forceinline__ float bf2f(u16 u) {
  union { unsigned int i; float f; } c;
  c.i = ((unsigned int)u) << 16;
  return c.f;
}
__device__ __forceinline__ float bflo(unsigned int u) {
  union { unsigned int i; float f; } c; c.i = u << 16; return c.f;
}
__device__ __forceinline__ float bfhi(unsigned int u) {
  union { unsigned int i; float f; } c; c.i = u & 0xffff0000u; return c.f;
}
__device__ __forceinline__ u16 f2bf(float f) {
  union { float f; unsigned int i; } c;
  c.f = f;
  unsigned int x = c.i;
  unsigned int r = (x + 0x7fffu + ((x >> 16) & 1u)) >> 16; // RNE
  return (u16)r;
}

// Destination-bin bounds for proj of supports (-10+0.4t)*wv, t=0..50, wv>=0.
__device__ __forceinline__ void proj_bounds(float wv, int& ML, int& MH) {
  float smin = (-10.0f + 0.4f * 0.0f)  * wv;
  float smax = (-10.0f + 0.4f * 50.0f) * wv;
  float bmin = (fminf(fmaxf(smin, -10.0f), 10.0f) + 10.0f) / 0.4f;
  float bmax = (fminf(fmaxf(smax, -10.0f), 10.0f) + 10.0f) / 0.4f;
  ML = (int)floorf(bmin);
  MH = (int)ceilf(bmax);
}

// ---------- atomic-free projection via segmented scan ----------
template<typename SUPP>
__device__ __forceinline__ void proj_scan(float* __restrict__ g1,
                                          float* __restrict__ g2,
                                          int span, int lane, SUPP supp)
{
  if (lane < 52) g1[lane] = 0.f;
  if (lane < 53) g2[lane] = 0.f;
  float cml = 0.f, cmu = 0.f;
  int ck = -1;
  for (int base = 0; base < span; base += 64) {
    int t = base + lane;
    bool act = (t < span);
    int tc = act ? t : (span - 1);
    float sup, p;
    supp(tc, act, sup, p);
    float c  = fminf(fmaxf(sup, -10.0f), 10.0f);
    float b  = (c + 10.0f) / 0.4f;
    float l  = floorf(b);
    float u  = ceilf(b);
    float eq = (u == l) ? 1.0f : 0.0f;
    float ml = p * (u - b + eq);
    float mu = p * (b - l);
    int   li = (int)l;
    bool last = (base + 64 >= span);
    if (lane == 0 && ck >= 0) {
      if (ck == li) { ml += cml; mu += cmu; }
      else          { g1[ck] = cml; g2[ck + 1] = cmu; }
    }
#pragma unroll
    for (int d = 1; d < 64; d <<= 1) {
      int   lo = __shfl_up(li, d);
      float a1 = __shfl_up(ml, d);
      float a2 = __shfl_up(mu, d);
      bool same = (lane >= d) && (lo == li);
      ml += same ? a1 : 0.f;
      mu += same ? a2 : 0.f;
    }
    int ln = __shfl_down(li, 1);
    bool runend = (lane == 63) ? last : (ln != li);
    if (runend) { g1[li] = ml; g2[li + 1] = mu; }
    if (!last) {
      cml = __shfl(ml, 63);
      cmu = __shfl(mu, 63);
      ck  = __shfl(li, 63);
    }
  }
}

// ---------- convolution: uniform-b128 kernel taps + batched q reads ----------
__device__ __forceinline__ void conv_pad2(const float* __restrict__ q,
                                          float* __restrict__ qn,
                                          const float* __restrict__ kvs,
                                          int ML, int W, int T,
                                          int LQ, int HQ, int tid, int nthr)
{
  const int Lout = LQ + ML, Hout = HQ + ML + T;
  for (int J = Lout + tid; J <= Hout; J += nthr) {
    const float* qp = q + (J - ML);
    float acc = 0.f;
    for (int c = 0; c < W; c += 4) {
      float4 k4 = *(const float4*)(kvs + c);   // uniform address -> broadcast
      acc = fmaf(k4.x, qp[-c],     acc);
      acc = fmaf(k4.y, qp[-c - 1], acc);
      acc = fmaf(k4.z, qp[-c - 2], acc);
      acc = fmaf(k4.w, qp[-c - 3], acc);
    }
    qn[J] = acc;
  }
}

// =================== Kernel 1: hypernet MLPs (+ inline dtype detect) ========
template<int BF>
__device__ __forceinline__ float ldt(const void* p, int i) {
  if (BF) return bf2f(((const u16*)p)[i]);
  return ((const float*)p)[i];
}

template<int BF>
__device__ __forceinline__ float dot128_t(const void* w, int row, const float* s) {
  float acc = 0.f;
  if (BF) {
    const uint4* p = (const uint4*)((const u16*)w + row * 128);
#pragma unroll
    for (int i = 0; i < 16; ++i) {
      uint4 v = p[i];
      int b = i * 8;
      acc = fmaf(bflo(v.x), s[b + 0], acc); acc = fmaf(bfhi(v.x), s[b + 1], acc);
      acc = fmaf(bflo(v.y), s[b + 2], acc); acc = fmaf(bfhi(v.y), s[b + 3], acc);
      acc = fmaf(bflo(v.z), s[b + 4], acc); acc = fmaf(bfhi(v.z), s[b + 5], acc);
      acc = fmaf(bflo(v.w), s[b + 6], acc); acc = fmaf(bfhi(v.w), s[b + 7], acc);
    }
  } else {
    const float4* p = (const float4*)((const float*)w + row * 128);
#pragma unroll
    for (int i = 0; i < 32; ++i) {
      float4 v = p[i];
      int b = i * 4;
      acc = fmaf(v.x, s[b + 0], acc); acc = fmaf(v.y, s[b + 1], acc);
      acc = fmaf(v.z, s[b + 2], acc); acc = fmaf(v.w, s[b + 3], acc);
    }
  }
  return acc;
}

template<int BF>
__device__ __forceinline__ float dot64_t(const void* w, int row, const float* h) {
  float acc = 0.f;
  if (BF) {
    const uint4* p = (const uint4*)((const u16*)w + row * 64);
#pragma unroll
    for (int i = 0; i < 8; ++i) {
      uint4 v = p[i];
      int b = i * 8;
      acc = fmaf(bflo(v.x), h[b + 0], acc); acc = fmaf(bfhi(v.x), h[b + 1], acc);
      acc = fmaf(bflo(v.y), h[b + 2], acc); acc = fmaf(bfhi(v.y), h[b + 3], acc);
      acc = fmaf(bflo(v.z), h[b + 4], acc); acc = fmaf(bfhi(v.z), h[b + 5], acc);
      acc = fmaf(bflo(v.w), h[b + 6], acc); acc = fmaf(bfhi(v.w), h[b + 7], acc);
    }
  } else {
    const float4* p = (const float4*)((const float*)w + row * 64);
#pragma unroll
    for (int i = 0; i < 16; ++i) {
      float4 v = p[i];
      int b = i * 4;
      acc = fmaf(v.x, h[b + 0], acc); acc = fmaf(v.y, h[b + 1], acc);
      acc = fmaf(v.z, h[b + 2], acc); acc = fmaf(v.w, h[b + 3], acc);
    }
  }
  return acc;
}

template<int BF>
__device__ __forceinline__ void mlp_body(
    const void* states,
    const void* hw1_w1, const void* hw1_b1, const void* hw1_w2, const void* hw1_b2,
    const void* hb1_w,  const void* hb1_b,
    const void* hwf_w1, const void* hwf_b1, const void* hwf_w2, const void* hwf_b2,
    const void* v_w1,   const void* v_b1,   const void* v_w2,   const void* v_b2,
    float* w1_ws, float* b1_ws, float* wf_ws, float* v_ws,
    int n, int tid, float* s, float* h1, float* hf, float* vh)
{
  s[tid]      = ldt<BF>(states, n * 128 + tid);
  s[tid + 64] = ldt<BF>(states, n * 128 + 64 + tid);
  __syncthreads();

  h1[tid] = fmaxf(dot128_t<BF>(hw1_w1, tid, s) + ldt<BF>(hw1_b1, tid), 0.f);
  hf[tid] = fmaxf(dot128_t<BF>(hwf_w1, tid, s) + ldt<BF>(hwf_b1, tid), 0.f);
  if (tid < 32) {
    vh[tid] = fmaxf(dot128_t<BF>(v_w1, tid, s) + ldt<BF>(v_b1, tid), 0.f);
    b1_ws[n * 32 + tid] = dot128_t<BF>(hb1_w, tid, s) + ldt<BF>(hb1_b, tid);
  }
  __syncthreads();

#pragma unroll
  for (int k = 0; k < 4; ++k) {
    int o = tid + 64 * k;
    w1_ws[n * 256 + o] = fabsf(dot64_t<BF>(hw1_w2, o, h1) + ldt<BF>(hw1_b2, o));
  }
  if (tid < 32)
    wf_ws[n * 32 + tid] = fabsf(dot64_t<BF>(hwf_w2, tid, hf) + ldt<BF>(hwf_b2, tid));
  if (tid == 0) {
    float acc = ldt<BF>(v_b2, 0);
    for (int e = 0; e < 32; ++e) acc = fmaf(ldt<BF>(v_w2, e), vh[e], acc);
    v_ws[n] = acc;
  }
}

__global__ __launch_bounds__(64) void k_mlp(
    const void* __restrict__ states,
    const void* __restrict__ hw1_w1, const void* __restrict__ hw1_b1,
    const void* __restrict__ hw1_w2, const void* __restrict__ hw1_b2,
    const void* __restrict__ hb1_w,  const void* __restrict__ hb1_b,
    const void* __restrict__ hwf_w1, const void* __restrict__ hwf_b1,
    const void* __restrict__ hwf_w2, const void* __restrict__ hwf_b2,
    const void* __restrict__ v_w1,   const void* __restrict__ v_b1,
    const void* __restrict__ v_w2,   const void* __restrict__ v_b2,
    float* __restrict__ w1_ws, float* __restrict__ b1_ws,
    float* __restrict__ wf_ws, float* __restrict__ v_ws,
    int* __restrict__ flag, int* __restrict__ cnt, int* __restrict__ done)
{
  __shared__ float s[128];
  __shared__ float h1[64];
  __shared__ float hf[64];
  __shared__ float vh[32];
  const int n = blockIdx.x;
  const int tid = threadIdx.x;

  // inline dtype detect on first 128 u16 words of states (~N(0,1), no zeros)
  const u16* sr = (const u16*)states;
  unsigned int e0 = (sr[tid] >> 7) & 0xFF;
  unsigned int e1 = (sr[tid + 64] >> 7) & 0xFF;
  unsigned long long bl0 = __ballot(e0 >= 97 && e0 <= 141);
  unsigned long long bl1 = __ballot(e1 >= 97 && e1 <= 141);
  int bf = (__popcll(bl0) + __popcll(bl1) >= 104) ? 1 : 0;
  if (tid == 0) { *flag = bf; cnt[n] = 0; done[n] = 0; }

  if (bf)
    mlp_body<1>(states, hw1_w1, hw1_b1, hw1_w2, hw1_b2, hb1_w, hb1_b,
                hwf_w1, hwf_b1, hwf_w2, hwf_b2, v_w1, v_b1, v_w2, v_b2,
                w1_ws, b1_ws, wf_ws, v_ws, n, tid, s, h1, hf, vh);
  else
    mlp_body<0>(states, hw1_w1, hw1_b1, hw1_w2, hw1_b2, hb1_w, hb1_b,
                hwf_w1, hwf_b1, hwf_w2, hwf_b2, v_w1, v_b1, v_w2, v_b2,
                w1_ws, b1_ws, wf_ws, v_ws, n, tid, s, h1, hf, vh);
}

// ======= Kernel 2: R10 core (gather projections) + FINISHER (split-K style):
// the 32nd arriving task block of sample n runs the whole 31-conv chain +
// final projection inline, overlapping k_final's work with remaining blocks.
// R13 bug fixed: finisher conv now uses data base 52 consistently (seed,
// reads, writes, final projection). =======
__global__ __launch_bounds__(128) void k_perembed(
    const void* __restrict__ aq,          // (1024, 8, 51)
    const float* __restrict__ w1_ws, const float* __restrict__ b1_ws,
    const float* __restrict__ wf_ws, const float* __restrict__ v_ws,
    float* __restrict__ xw_ws, void* __restrict__ out,
    const int* __restrict__ flag, int* __restrict__ cnt, int* __restrict__ done)
{
  // arena[w]: task conv A = [0..620), B = [620..1240). Finisher reuses the
  // row as fA (data base 52) and fB (data base 620+52); whole row pre-zeroed.
  __shared__ __align__(16) float arena[2][1240];
  __shared__ __align__(16) float kv_all[2][8][16];
  __shared__ __align__(16) float kvo[2][56];
  __shared__ float p_lds[2][8][52];
  __shared__ float gAb[2][53];
  __shared__ float gBb[2][54];

  const int w    = threadIdx.x >> 6;
  const int lane = threadIdx.x & 63;
  const int task = blockIdx.x * 2 + w;
  const int n = task >> 5;
  const int e = task & 31;
  const int bf = *flag;

  float* A   = arena[w];
  float* B   = arena[w] + 620;
  float* gA  = gAb[w];
  float* gB  = gBb[w];
  float (*pl)[52] = p_lds[w];

  // ---- stage agent probs into LDS ----
  if (bf) {
    const u16* p = (const u16*)aq + n * 408 + lane;
    if (lane < 51) {
#pragma unroll
      for (int a = 0; a < 8; ++a) pl[a][lane] = bf2f(p[a * 51]);
    }
  } else {
    const float* p = (const float*)aq + n * 408 + lane;
    if (lane < 51) {
#pragma unroll
      for (int a = 0; a < 8; ++a) pl[a][lane] = p[a * 51];
    }
  }
  float wreg = (lane < 8) ? w1_ws[n * 256 + e * 8 + lane] : 0.f;
  float b1v  = b1_ws[n * 32 + e];
  float wfv  = wf_ws[n * 32 + e];

  int mlA = 0, mhA = 0;
  if (lane < 8) proj_bounds(wreg, mlA, mhA);
  unsigned long long wide = __ballot((lane < 8) && (mhA - mlA > 15));
  WAVE_SYNC();                            // p_lds visible

  int LQ, HQ;
  float* q = A;
  float* qn = B;

  if (wide == 0ull) {
    // ================= gather path (R10) =================
#pragma unroll
    for (int r = 0; r < 2; ++r) {
      int a  = 4 * r + (lane >> 4);
      int jj = lane & 15;
      float wv = __shfl(wreg, a);
      int ML = __shfl(mlA, a);
      int MH = __shfl(mhA, a);
      int T = MH - ML;
      int j = ML + jj;
      float ej  = 0.4f * (float)j - 10.0f;
      float e25 = ej * 2.5f;
      float invw = 2.5f / wv;
      int tL = (jj == 0) ? 0  : (int)floorf((ej - 0.4f) * invw + 25.f) - 1;
      int tH = (jj >= T) ? 50 : (int)ceilf ((ej + 0.4f) * invw + 25.f) + 1;
      tL = tL < 0 ? 0 : tL;
      tH = tH > 50 ? 50 : tH;
      if (jj > T) { tL = 0; tH = -1; }
      float step = 0.4f * wv;
      float sup  = fmaf((float)tL, step, -10.0f * wv);
      float acc = 0.f;
      const float* pb = pl[a];
      for (int t = tL; t <= tH; ++t) {
        float c   = fminf(fmaxf(sup, -10.0f), 10.0f);
        float d   = fmaf(c, 2.5f, -e25);
        float wgt = fmaxf(0.f, 1.0f - fabsf(d));
        acc = fmaf(pb[t], wgt, acc);
        sup += step;
      }
      kv_all[w][a][jj] = (jj <= T) ? acc : 0.f;
    }
    WAVE_SYNC();

    int ML0 = __shfl(mlA, 0), MH0 = __shfl(mhA, 0);
    if (lane <= MH0 - ML0) A[64 + ML0 + lane] = kv_all[w][0][lane];
    WAVE_SYNC();
    LQ = 64 + ML0; HQ = 64 + MH0;

#pragma unroll
    for (int a = 1; a < 8; ++a) {
      int ML = __shfl(mlA, a), MH = __shfl(mhA, a);
      int T = MH - ML;
      int W = (T + 4) & ~3;
      if (lane < W - 1) q[LQ - 1 - lane] = 0.f;
      if (lane < T)     q[HQ + 1 + lane] = 0.f;
      WAVE_SYNC();
      conv_pad2(q, qn, &kv_all[w][a][0], ML, W, T, LQ, HQ, lane, 64);
      WAVE_SYNC();
      LQ += ML; HQ += MH;
      float* t_ = q; q = qn; qn = t_;
    }
  } else {
    // ================= fallback: proven scan path =================
    float* kvs = kvo[w];
    float wv0 = __shfl(wreg, 0);
    int ML0 = __shfl(mlA, 0), MH0 = __shfl(mhA, 0);
    proj_scan(gA, gB, 51, lane, [&](int t, bool act, float& sup, float& p) {
      sup = (-10.0f + 0.4f * (float)t) * wv0;
      float pv = pl[0][t];
      p = act ? pv : 0.f;
    });
    if (lane <= MH0 - ML0)
      A[64 + ML0 + lane] = gA[ML0 + lane] + gB[ML0 + lane];
    WAVE_SYNC();
    LQ = 64 + ML0; HQ = 64 + MH0;

    for (int a = 1; a < 8; ++a) {
      float wv = __shfl(wreg, a);
      int ML = __shfl(mlA, a), MH = __shfl(mhA, a);
      int T = MH - ML;
      int W = (T + 4) & ~3;
      proj_scan(gA, gB, 51, lane, [&](int t, bool act, float& sup, float& p) {
        sup = (-10.0f + 0.4f * (float)t) * wv;
        float pv = pl[a][t];
        p = act ? pv : 0.f;
      });
      if (lane < W)     kvs[lane] = (lane <= T) ? (gA[ML + lane] + gB[ML + lane]) : 0.f;
      if (lane < W - 1) q[LQ - 1 - lane] = 0.f;
      if (lane < T)     q[HQ + 1 + lane] = 0.f;
      WAVE_SYNC();
      conv_pad2(q, qn, kvs, ML, W, T, LQ, HQ, lane, 64);
      WAVE_SYNC();
      LQ += ML; HQ += MH;
      float* t_ = q; q = qn; qn = t_;
    }
  }

  // ---- elu projection (chunked scan over claimed span) ----
  {
    int span = HQ - LQ + 1;
    int LQl = LQ;
    const float* qf = q;
    proj_scan(gA, gB, span, lane, [&](int t, bool act, float& sup, float& p) {
      int tg = (LQl - 64) + t;            // grid index in [0,400]
      float raw = (-80.0f + 0.4f * (float)tg) + b1v;
      sup = (raw > 0.f) ? raw : expm1f(raw);
      p = act ? qf[LQl + t] : 0.f;
    });
  }
  WAVE_SYNC();

  // ---- wf projection: x2 (in gA/gB) -> xw ----
  float x2v = (lane < 51) ? (gA[lane] + gB[lane]) : 0.f;
  WAVE_SYNC();                            // fence: read before re-zero
  int MLf, MHf;
  proj_bounds(wfv, MLf, MHf);
  proj_scan(gA, gB, 51, lane, [&](int t, bool act, float& sup, float& p) {
    sup = (-10.0f + 0.4f * (float)t) * wfv;
    p = act ? x2v : 0.f;
  });
  WAVE_SYNC();
  if (lane <= MHf - MLf)
    xw_ws[task * 51 + MLf + lane] = gA[MLf + lane] + gB[MLf + lane];

  // ======== FINISHER: last-arriving task block completes sample n ========
  __threadfence();                        // release xw row (device scope)
  int old = 0;
  if (lane == 0) old = atomicAdd(&cnt[n], 1);
  old = __shfl(old, 0);
  if (old != 31) return;
  __threadfence();                        // acquire: 31 other xw rows visible

  // per-row bounds (lanes 0..31) and totals
  float wfr = (lane < 32) ? wf_ws[n * 32 + lane] : 0.f;
  int rml = 0, rmh = 0;
  if (lane < 32) proj_bounds(wfr, rml, rmh);
  int sml = rml, smh = rmh;
#pragma unroll
  for (int d = 1; d < 32; d <<= 1) { sml += __shfl_xor(sml, d); smh += __shfl_xor(smh, d); }
  sml = __shfl(sml, 0); smh = __shfl(smh, 0);
  int Ltot = smh - sml + 1;
  if (Ltot > 560) return;                 // overflow: leave for k_final (done=0)
  float vv = v_ws[n];

  // re-use arena as chain buffers (task data dead now); full pre-zero.
  // DATA BASE = 52 in both halves (max W-1 = 51 left reads stay in-bounds).
  float* fA = arena[w] + 52;
  float* fB = arena[w] + 620 + 52;
  float* kvf = kvo[w];
  {
    float4 z = make_float4(0.f, 0.f, 0.f, 0.f);
    float4* a4 = (float4*)arena[w];
    for (int i = lane; i < 310; i += 64) a4[i] = z;
  }

  int ml0 = __shfl(rml, 0), mh0 = __shfl(rmh, 0);
  int L = mh0 - ml0 + 1;
  // prefetch row 1
  int mlN = __shfl(rml, 1), mhN = __shfl(rmh, 1);
  float nv = (lane <= mhN - mlN) ? xw_ws[(n * 32 + 1) * 51 + mlN + lane] : 0.f;
  WAVE_SYNC();                            // zeros visible
  if (lane < L) fA[lane] = xw_ws[(n * 32 + 0) * 51 + ml0 + lane];
  WAVE_SYNC();

  float* fq = fA;
  float* fqn = fB;
  for (int j = 1; j < 32; ++j) {
    int T = mhN - mlN;
    int W = (T + 4) & ~3;
    if (lane < W) kvf[lane] = (lane <= T) ? nv : 0.f;
    if (j < 31) {                         // next row load overlaps conv
      mlN = __shfl(rml, j + 1); mhN = __shfl(rmh, j + 1);
      nv = (lane <= mhN - mlN) ? xw_ws[(n * 32 + j + 1) * 51 + mlN + lane] : 0.f;
    }
    WAVE_SYNC();
    // out[o] = sum_{i=0..T} kv[i] * q[o-i], o in [0, L+T). Reads below 0 hit
    // the 52-elem zero apron; reads beyond extent hit pre-zeroed never-
    // written region (extents grow monotonically across buffer reuses).
    int Lout = L + T;
    for (int o = lane; o < Lout; o += 64) {
      const float* qp = fq + o;
      float acc = 0.f;
      for (int c = 0; c < W; c += 4) {
        float4 k4 = *(const float4*)(kvf + c);
        acc = fmaf(k4.x, qp[-c],     acc);
        acc = fmaf(k4.y, qp[-c - 1], acc);
        acc = fmaf(k4.z, qp[-c - 2], acc);
        acc = fmaf(k4.w, qp[-c - 3], acc);
      }
      fqn[o] = acc;
    }
    WAVE_SYNC();
    L = Lout;
    float* t_ = fq; fq = fqn; fqn = t_;
  }

  // final projection over claimed support [sml, smh]
  {
    int span = L;
    const float* qf = fq;
    int mlt = sml;
    proj_scan(gA, gB, span, lane, [&](int t, bool act, float& sup, float& p) {
      int tg = mlt + t;                   // grid index in [0,1600]
      sup = (-320.0f + 0.4f * (float)tg) + vv;
      p = act ? qf[t] : 0.f;
    });
  }
  WAVE_SYNC();
  if (lane < 51) {
    float o = gA[lane] + gB[lane];
    if (bf) ((u16*)out)[n * 51 + lane] = f2bf(o);
    else    ((float*)out)[n * 51 + lane] = o;
  }
  if (lane == 0) done[n] = 1;             // visible to k_final via kernel boundary
}

// ====== Kernel 3: TREE convolution — safety net; early-exit if finisher ran ==
__global__ __launch_bounds__(256) void k_final(
    const float* __restrict__ xw_ws, const float* __restrict__ wf_ws,
    const float* __restrict__ v_ws,
    void* __restrict__ out, const int* __restrict__ flag,
    const int* __restrict__ done)
{
  __shared__ __align__(16) float bufA[4608];
  __shared__ __align__(16) float bufB[4608];
  __shared__ int meta_s[63];
  __shared__ int meta_l[63];
  __shared__ int meta_ml[32];
  __shared__ int meta_g[6];
  __shared__ int meta_mltot;
  __shared__ float gA[53], gB[54];

  const int n    = blockIdx.x;
  if (done[n] != 0) return;               // uniform: finisher already wrote out

  const int tid  = threadIdx.x;
  const int lane = tid & 63;
  const int bf   = *flag;

  float wfreg = (lane < 32) ? wf_ws[n * 32 + lane] : 0.f;
  float vv    = v_ws[n];

  {
    float4 z = make_float4(0.f, 0.f, 0.f, 0.f);
    float4* a4 = (float4*)bufA;
    float4* b4 = (float4*)bufB;
    for (int i = tid; i < 1152; i += 256) { a4[i] = z; b4[i] = z; }
  }

  {
    int ml, mh;
    proj_bounds(wfreg, ml, mh);
    if (lane < 32) meta_ml[lane] = ml;
    int msum = ml;
#pragma unroll
    for (int d = 1; d < 32; d <<= 1) msum += __shfl_xor(msum, d);
    if (lane == 0) meta_mltot = msum;

    int curlen = mh - ml + 1;
    int base = 0, Ncur = 32;
#pragma unroll
    for (int c = 0; c <= 5; ++c) {
      int lm = (lane < Ncur) ? curlen : 0;
#pragma unroll
      for (int d = 1; d < 32; d <<= 1) {
        int o = __shfl_xor(lm, d);
        lm = (o > lm) ? o : lm;
      }
      int G = (lm + 11) & ~3;
      int sp = ((curlen + 3) & ~3) + G;
      int inc = (lane < Ncur) ? sp : 0;
      int v0 = inc;
#pragma unroll
      for (int d = 1; d < 32; d <<= 1) {
        int u = __shfl_up(inc, d);
        if (lane >= d && lane < 32) inc += u;
      }
      if (lane < Ncur) {
        meta_s[base + lane] = 832 + (inc - v0);
        meta_l[base + lane] = curlen;
      }
      if (lane == 0) meta_g[c] = G;
      if (c < 5) {
        int l0 = __shfl(curlen, 2 * lane);
        int l1 = __shfl(curlen, 2 * lane + 1);
        curlen = l0 + l1 - 1;
        base += Ncur;
        Ncur >>= 1;
      }
    }
  }
  __syncthreads();

  {
    int g = tid >> 3, i = tid & 7;
    int s = meta_s[g], l = meta_l[g], ml = meta_ml[g];
    const float* row = xw_ws + (n * 32 + g) * 51 + ml;
    for (int i0 = i; i0 < l; i0 += 8) bufA[s + i0] = row[i0];
  }
  __syncthreads();

#pragma unroll
  for (int c = 1; c <= 5; ++c) {
    const float* bin = (c & 1) ? bufA : bufB;
    float*       bout = (c & 1) ? bufB : bufA;
    const int Nout = 32 >> c;
    const int lg = 3 + c;
    const int gs = 1 << lg;
    const int k  = tid >> lg;
    const int st = tid & (gs - 1);
    const int bc = 64 - (64 >> c);
    const int bp = 64 - (64 >> (c - 1));
    const int i0 = bp + 2 * k;
    const int sA = meta_s[i0];
    const int sB = meta_s[i0 + 1];
    const int lB = meta_l[i0 + 1];
    const int sO = meta_s[bc + k];
    const int lO = meta_l[bc + k];
    const int W  = (lB + 3) & ~3;

    for (int j = st * 2; j < lO; j += gs * 2) {
      const float* Ap = bin + sA + j + 1;
      float a0 = 0.f, a1 = 0.f;
      for (int m = 0; m < W; m += 4) {
        float4 k4 = *(const float4*)(bin + sB + m);
        float v0 = Ap[-m], v1 = Ap[-m - 1], v2 = Ap[-m - 2];
        float v3 = Ap[-m - 3], v4 = Ap[-m - 4];
        a0 = fmaf(k4.x, v1, fmaf(k4.y, v2, fmaf(k4.z, v3, fmaf(k4.w, v4, a0))));
        a1 = fmaf(k4.x, v0, fmaf(k4.y, v1, fmaf(k4.z, v2, fmaf(k4.w, v3, a1))));
      }
      bout[sO + j] = a0;
      if (j + 1 < lO) bout[sO + j + 1] = a1;
    }

    if (c >= 2 && c <= 4) {
      int G = meta_g[c];
      for (int p = tid; p < G; p += 256) bout[832 - G + p] = 0.f;
      for (int k2 = 0; k2 < Nout; ++k2) {
        int ss = meta_s[bc + k2] + meta_l[bc + k2];
        int ee = (k2 + 1 < Nout) ? meta_s[bc + k2 + 1]
                                 : ss + G + 3;
        for (int p = ss + tid; p < ee; p += 256) bout[p] = 0.f;
      }
    }
    __syncthreads();
  }

  if (tid < 64) {
    int s5 = meta_s[62], l5 = meta_l[62], mlt = meta_mltot;
    const float* qf = bufB + s5;
    proj_scan(gA, gB, l5, lane, [&](int t, bool act, float& sup, float& p) {
      int tg = mlt + t;
      sup = (-320.0f + 0.4f * (float)tg) + vv;
      p = act ? qf[t] : 0.f;
    });
    WAVE_SYNC();
    if (lane < 51) {
      float o = gA[lane] + gB[lane];
      if (bf) ((u16*)out)[n * 51 + lane] = f2bf(o);
      else    ((float*)out)[n * 51 + lane] = o;
    }
  }
}

// =========================== launcher ===========================
extern "C" void kernel_launch(void* const* d_in, const int* in_sizes, int n_in,
                              void* d_out, int out_size, void* d_ws, size_t ws_size,
                              hipStream_t stream)
{
  float* ws    = (float*)d_ws;
  float* w1_ws = ws;                       // 1024*256
  float* b1_ws = w1_ws + 1024 * 256;       // 1024*32
  float* wf_ws = b1_ws + 1024 * 32;        // 1024*32
  float* v_ws  = wf_ws + 1024 * 32;        // 1024
  float* xw_ws = v_ws  + 1024;             // 1024*32*51
  int*   flag  = (int*)(xw_ws + 1024 * 32 * 51);
  int*   cnt   = flag + 1;                 // 1024 sample counters
  int*   done  = cnt + 1024;               // 1024 done flags

  k_mlp<<<1024, 64, 0, stream>>>(d_in[1],
      d_in[2], d_in[3], d_in[4], d_in[5], d_in[6], d_in[7],
      d_in[8], d_in[9], d_in[10], d_in[11], d_in[12], d_in[13],
      d_in[14], d_in[15],
      w1_ws, b1_ws, wf_ws, v_ws, flag, cnt, done);

  k_perembed<<<16384, 128, 0, stream>>>(d_in[0], w1_ws, b1_ws, wf_ws, v_ws,
                                        xw_ws, d_out, flag, cnt, done);

  k_final<<<1024, 256, 0, stream>>>(xw_ws, wf_ws, v_ws, d_out, flag, done);
}

// Round 15
// 246.189 us; speedup vs baseline: 3.5912x; 3.5912x over previous
//
#include <hip/hip_runtime.h>
#include <hip/hip_bf16.h>
#include <math.h>

typedef unsigned short u16;

// Compiler memory fence + drain of this wave's LDS ops. Each task's LDS region
// is touched by exactly ONE wave; same-wave DS ops execute in order.
#define WAVE_SYNC() asm volatile("s_waitcnt lgkmcnt(0)" ::: "memory")

// ---------- dtype helpers ----------
__device__ __forceinline__ float bf2f(u16 u) {
  union { unsigned int i; float f; } c;
  c.i = ((unsigned int)u) << 16;
  return c.f;
}
__device__ __forceinline__ float bflo(unsigned int u) {
  union { unsigned int i; float f; } c; c.i = u << 16; return c.f;
}
__device__ __forceinline__ float bfhi(unsigned int u) {
  union { unsigned int i; float f; } c; c.i = u & 0xffff0000u; return c.f;
}
__device__ __forceinline__ u16 f2bf(float f) {
  union { float f; unsigned int i; } c;
  c.f = f;
  unsigned int x = c.i;
  unsigned int r = (x + 0x7fffu + ((x >> 16) & 1u)) >> 16; // RNE
  return (u16)r;
}

// Destination-bin bounds for proj of supports (-10+0.4t)*wv, t=0..50, wv>=0.
__device__ __forceinline__ void proj_bounds(float wv, int& ML, int& MH) {
  float smin = (-10.0f + 0.4f * 0.0f)  * wv;
  float smax = (-10.0f + 0.4f * 50.0f) * wv;
  float bmin = (fminf(fmaxf(smin, -10.0f), 10.0f) + 10.0f) / 0.4f;
  float bmax = (fminf(fmaxf(smax, -10.0f), 10.0f) + 10.0f) / 0.4f;
  ML = (int)floorf(bmin);
  MH = (int)ceilf(bmax);
}

// ---------- atomic-free projection via segmented scan (fallback + elu/wf) ---
template<typename SUPP>
__device__ __forceinline__ void proj_scan(float* __restrict__ g1,
                                          float* __restrict__ g2,
                                          int span, int lane, SUPP supp)
{
  if (lane < 52) g1[lane] = 0.f;
  if (lane < 53) g2[lane] = 0.f;
  float cml = 0.f, cmu = 0.f;
  int ck = -1;
  for (int base = 0; base < span; base += 64) {
    int t = base + lane;
    bool act = (t < span);
    int tc = act ? t : (span - 1);
    float sup, p;
    supp(tc, act, sup, p);
    float c  = fminf(fmaxf(sup, -10.0f), 10.0f);
    float b  = (c + 10.0f) / 0.4f;
    float l  = floorf(b);
    float u  = ceilf(b);
    float eq = (u == l) ? 1.0f : 0.0f;
    float ml = p * (u - b + eq);
    float mu = p * (b - l);
    int   li = (int)l;
    bool last = (base + 64 >= span);
    if (lane == 0 && ck >= 0) {
      if (ck == li) { ml += cml; mu += cmu; }
      else          { g1[ck] = cml; g2[ck + 1] = cmu; }
    }
#pragma unroll
    for (int d = 1; d < 64; d <<= 1) {
      int   lo = __shfl_up(li, d);
      float a1 = __shfl_up(ml, d);
      float a2 = __shfl_up(mu, d);
      bool same = (lane >= d) && (lo == li);
      ml += same ? a1 : 0.f;
      mu += same ? a2 : 0.f;
    }
    int ln = __shfl_down(li, 1);
    bool runend = (lane == 63) ? last : (ln != li);
    if (runend) { g1[li] = ml; g2[li + 1] = mu; }
    if (!last) {
      cml = __shfl(ml, 63);
      cmu = __shfl(mu, 63);
      ck  = __shfl(li, 63);
    }
  }
}

// ---------- convolution: uniform-b128 kernel taps + batched q reads ----------
__device__ __forceinline__ void conv_pad2(const float* __restrict__ q,
                                          float* __restrict__ qn,
                                          const float* __restrict__ kvs,
                                          int ML, int W, int T,
                                          int LQ, int HQ, int tid, int nthr)
{
  const int Lout = LQ + ML, Hout = HQ + ML + T;
  for (int J = Lout + tid; J <= Hout; J += nthr) {
    const float* qp = q + (J - ML);
    float acc = 0.f;
    for (int c = 0; c < W; c += 4) {
      float4 k4 = *(const float4*)(kvs + c);   // uniform address -> broadcast
      acc = fmaf(k4.x, qp[-c],     acc);
      acc = fmaf(k4.y, qp[-c - 1], acc);
      acc = fmaf(k4.z, qp[-c - 2], acc);
      acc = fmaf(k4.w, qp[-c - 3], acc);
    }
    qn[J] = acc;
  }
}

// =================== Kernel 1: hypernet MLPs (+ inline dtype detect) ========
template<int BF>
__device__ __forceinline__ float ldt(const void* p, int i) {
  if (BF) return bf2f(((const u16*)p)[i]);
  return ((const float*)p)[i];
}

template<int BF>
__device__ __forceinline__ float dot128_t(const void* w, int row, const float* s) {
  float acc = 0.f;
  if (BF) {
    const uint4* p = (const uint4*)((const u16*)w + row * 128);
#pragma unroll
    for (int i = 0; i < 16; ++i) {
      uint4 v = p[i];
      int b = i * 8;
      acc = fmaf(bflo(v.x), s[b + 0], acc); acc = fmaf(bfhi(v.x), s[b + 1], acc);
      acc = fmaf(bflo(v.y), s[b + 2], acc); acc = fmaf(bfhi(v.y), s[b + 3], acc);
      acc = fmaf(bflo(v.z), s[b + 4], acc); acc = fmaf(bfhi(v.z), s[b + 5], acc);
      acc = fmaf(bflo(v.w), s[b + 6], acc); acc = fmaf(bfhi(v.w), s[b + 7], acc);
    }
  } else {
    const float4* p = (const float4*)((const float*)w + row * 128);
#pragma unroll
    for (int i = 0; i < 32; ++i) {
      float4 v = p[i];
      int b = i * 4;
      acc = fmaf(v.x, s[b + 0], acc); acc = fmaf(v.y, s[b + 1], acc);
      acc = fmaf(v.z, s[b + 2], acc); acc = fmaf(v.w, s[b + 3], acc);
    }
  }
  return acc;
}

template<int BF>
__device__ __forceinline__ float dot64_t(const void* w, int row, const float* h) {
  float acc = 0.f;
  if (BF) {
    const uint4* p = (const uint4*)((const u16*)w + row * 64);
#pragma unroll
    for (int i = 0; i < 8; ++i) {
      uint4 v = p[i];
      int b = i * 8;
      acc = fmaf(bflo(v.x), h[b + 0], acc); acc = fmaf(bfhi(v.x), h[b + 1], acc);
      acc = fmaf(bflo(v.y), h[b + 2], acc); acc = fmaf(bfhi(v.y), h[b + 3], acc);
      acc = fmaf(bflo(v.z), h[b + 4], acc); acc = fmaf(bfhi(v.z), h[b + 5], acc);
      acc = fmaf(bflo(v.w), h[b + 6], acc); acc = fmaf(bfhi(v.w), h[b + 7], acc);
    }
  } else {
    const float4* p = (const float4*)((const float*)w + row * 64);
#pragma unroll
    for (int i = 0; i < 16; ++i) {
      float4 v = p[i];
      int b = i * 4;
      acc = fmaf(v.x, h[b + 0], acc); acc = fmaf(v.y, h[b + 1], acc);
      acc = fmaf(v.z, h[b + 2], acc); acc = fmaf(v.w, h[b + 3], acc);
    }
  }
  return acc;
}

template<int BF>
__device__ __forceinline__ void mlp_body(
    const void* states,
    const void* hw1_w1, const void* hw1_b1, const void* hw1_w2, const void* hw1_b2,
    const void* hb1_w,  const void* hb1_b,
    const void* hwf_w1, const void* hwf_b1, const void* hwf_w2, const void* hwf_b2,
    const void* v_w1,   const void* v_b1,   const void* v_w2,   const void* v_b2,
    float* w1_ws, float* b1_ws, float* wf_ws, float* v_ws,
    int n, int tid, float* s, float* h1, float* hf, float* vh)
{
  s[tid]      = ldt<BF>(states, n * 128 + tid);
  s[tid + 64] = ldt<BF>(states, n * 128 + 64 + tid);
  __syncthreads();

  h1[tid] = fmaxf(dot128_t<BF>(hw1_w1, tid, s) + ldt<BF>(hw1_b1, tid), 0.f);
  hf[tid] = fmaxf(dot128_t<BF>(hwf_w1, tid, s) + ldt<BF>(hwf_b1, tid), 0.f);
  if (tid < 32) {
    vh[tid] = fmaxf(dot128_t<BF>(v_w1, tid, s) + ldt<BF>(v_b1, tid), 0.f);
    b1_ws[n * 32 + tid] = dot128_t<BF>(hb1_w, tid, s) + ldt<BF>(hb1_b, tid);
  }
  __syncthreads();

#pragma unroll
  for (int k = 0; k < 4; ++k) {
    int o = tid + 64 * k;
    w1_ws[n * 256 + o] = fabsf(dot64_t<BF>(hw1_w2, o, h1) + ldt<BF>(hw1_b2, o));
  }
  if (tid < 32)
    wf_ws[n * 32 + tid] = fabsf(dot64_t<BF>(hwf_w2, tid, hf) + ldt<BF>(hwf_b2, tid));
  if (tid == 0) {
    float acc = ldt<BF>(v_b2, 0);
    for (int e = 0; e < 32; ++e) acc = fmaf(ldt<BF>(v_w2, e), vh[e], acc);
    v_ws[n] = acc;
  }
}

__global__ __launch_bounds__(64) void k_mlp(
    const void* __restrict__ states,
    const void* __restrict__ hw1_w1, const void* __restrict__ hw1_b1,
    const void* __restrict__ hw1_w2, const void* __restrict__ hw1_b2,
    const void* __restrict__ hb1_w,  const void* __restrict__ hb1_b,
    const void* __restrict__ hwf_w1, const void* __restrict__ hwf_b1,
    const void* __restrict__ hwf_w2, const void* __restrict__ hwf_b2,
    const void* __restrict__ v_w1,   const void* __restrict__ v_b1,
    const void* __restrict__ v_w2,   const void* __restrict__ v_b2,
    float* __restrict__ w1_ws, float* __restrict__ b1_ws,
    float* __restrict__ wf_ws, float* __restrict__ v_ws,
    int* __restrict__ flag)
{
  __shared__ float s[128];
  __shared__ float h1[64];
  __shared__ float hf[64];
  __shared__ float vh[32];
  const int n = blockIdx.x;
  const int tid = threadIdx.x;

  // inline dtype detect on first 128 u16 words of states (~N(0,1), no zeros)
  const u16* sr = (const u16*)states;
  unsigned int e0 = (sr[tid] >> 7) & 0xFF;
  unsigned int e1 = (sr[tid + 64] >> 7) & 0xFF;
  unsigned long long bl0 = __ballot(e0 >= 97 && e0 <= 141);
  unsigned long long bl1 = __ballot(e1 >= 97 && e1 <= 141);
  int bf = (__popcll(bl0) + __popcll(bl1) >= 104) ? 1 : 0;
  if (tid == 0) *flag = bf;   // all blocks write same value (benign)

  if (bf)
    mlp_body<1>(states, hw1_w1, hw1_b1, hw1_w2, hw1_b2, hb1_w, hb1_b,
                hwf_w1, hwf_b1, hwf_w2, hwf_b2, v_w1, v_b1, v_w2, v_b2,
                w1_ws, b1_ws, wf_ws, v_ws, n, tid, s, h1, hf, vh);
  else
    mlp_body<0>(states, hw1_w1, hw1_b1, hw1_w2, hw1_b2, hb1_w, hb1_b,
                hwf_w1, hwf_b1, hwf_w2, hwf_b2, v_w1, v_b1, v_w2, v_b2,
                w1_ws, b1_ws, wf_ws, v_ws, n, tid, s, h1, hf, vh);
}

// ======= Kernel 2: 2 tasks per 128-thread block, one wave per task.
// Agent projections via FUSED GATHER (4 agents x 16 bins x 2 rounds):
// bin j receives p*max(0, 1-|b(t)-j|) — the continuous form of the C51
// scatter weights. Tasks with any agent span>15 fall back to the scan path.
// This is the measured-best k_perembed core (R10: 121 us, VALUBusy 77%). =======
__global__ __launch_bounds__(128) void k_perembed(
    const void* __restrict__ aq,          // (1024, 8, 51)
    const float* __restrict__ w1_ws, const float* __restrict__ b1_ws,
    const float* __restrict__ wf_ws, float* __restrict__ xw_ws,
    const int* __restrict__ flag)
{
  __shared__ __align__(16) float Ab[2][520];
  __shared__ __align__(16) float Bb[2][520];
  __shared__ __align__(16) float kv_all[2][8][16]; // gather-path kernels
  __shared__ __align__(16) float kvo[2][56];       // fallback kernel buffer
  __shared__ float p_lds[2][8][52];                // agent probs (row conflict-free)
  __shared__ float gAb[2][53];
  __shared__ float gBb[2][54];

  const int w    = threadIdx.x >> 6;
  const int lane = threadIdx.x & 63;
  const int task = blockIdx.x * 2 + w;
  const int n = task >> 5;
  const int e = task & 31;
  const int bf = *flag;

  float* A   = Ab[w];
  float* B   = Bb[w];
  float* gA  = gAb[w];
  float* gB  = gBb[w];
  float (*pl)[52] = p_lds[w];

  // ---- stage agent probs into LDS ----
  if (bf) {
    const u16* p = (const u16*)aq + n * 408 + lane;
    if (lane < 51) {
#pragma unroll
      for (int a = 0; a < 8; ++a) pl[a][lane] = bf2f(p[a * 51]);
    }
  } else {
    const float* p = (const float*)aq + n * 408 + lane;
    if (lane < 51) {
#pragma unroll
      for (int a = 0; a < 8; ++a) pl[a][lane] = p[a * 51];
    }
  }
  float wreg = (lane < 8) ? w1_ws[n * 256 + e * 8 + lane] : 0.f;
  float b1v  = b1_ws[n * 32 + e];
  float wfv  = wf_ws[n * 32 + e];

  // lanes 0..7: per-agent bounds
  int mlA = 0, mhA = 0;
  if (lane < 8) proj_bounds(wreg, mlA, mhA);
  unsigned long long wide = __ballot((lane < 8) && (mhA - mlA > 15));
  WAVE_SYNC();                            // p_lds visible for gather/scan

  int LQ, HQ;
  float* q = A;
  float* qn = B;

  if (wide == 0ull) {
    // ================= gather path =================
#pragma unroll
    for (int r = 0; r < 2; ++r) {
      int a  = 4 * r + (lane >> 4);
      int jj = lane & 15;
      float wv = __shfl(wreg, a);
      int ML = __shfl(mlA, a);
      int MH = __shfl(mhA, a);
      int T = MH - ML;
      int j = ML + jj;
      float ej  = 0.4f * (float)j - 10.0f;  // value of bin-j center edge
      float e25 = ej * 2.5f;
      float invw = 2.5f / wv;               // inf ok
      int tL = (jj == 0) ? 0  : (int)floorf((ej - 0.4f) * invw + 25.f) - 1;
      int tH = (jj >= T) ? 50 : (int)ceilf ((ej + 0.4f) * invw + 25.f) + 1;
      tL = tL < 0 ? 0 : tL;
      tH = tH > 50 ? 50 : tH;
      if (jj > T) { tL = 0; tH = -1; }      // inactive lane
      float step = 0.4f * wv;
      float sup  = fmaf((float)tL, step, -10.0f * wv);
      float acc = 0.f;
      const float* pb = pl[a];
      for (int t = tL; t <= tH; ++t) {
        float c   = fminf(fmaxf(sup, -10.0f), 10.0f);
        float d   = fmaf(c, 2.5f, -e25);    // ~ b - j (continuous weight)
        float wgt = fmaxf(0.f, 1.0f - fabsf(d));
        acc = fmaf(pb[t], wgt, acc);
        sup += step;
      }
      kv_all[w][a][jj] = (jj <= T) ? acc : 0.f;
    }
    WAVE_SYNC();

    // seed: agent 0 row into A (base 64)
    int ML0 = __shfl(mlA, 0), MH0 = __shfl(mhA, 0);
    if (lane <= MH0 - ML0) A[64 + ML0 + lane] = kv_all[w][0][lane];
    WAVE_SYNC();
    LQ = 64 + ML0; HQ = 64 + MH0;

#pragma unroll
    for (int a = 1; a < 8; ++a) {
      int ML = __shfl(mlA, a), MH = __shfl(mhA, a);
      int T = MH - ML;
      int W = (T + 4) & ~3;                // <= 16 in this path
      if (lane < W - 1) q[LQ - 1 - lane] = 0.f;
      if (lane < T)     q[HQ + 1 + lane] = 0.f;
      WAVE_SYNC();
      conv_pad2(q, qn, &kv_all[w][a][0], ML, W, T, LQ, HQ, lane, 64);
      WAVE_SYNC();
      LQ += ML; HQ += MH;
      float* t_ = q; q = qn; qn = t_;
    }
  } else {
    // ================= fallback: proven scan path =================
    float* kvs = kvo[w];
    float wv0 = __shfl(wreg, 0);
    int ML0 = __shfl(mlA, 0), MH0 = __shfl(mhA, 0);
    proj_scan(gA, gB, 51, lane, [&](int t, bool act, float& sup, float& p) {
      sup = (-10.0f + 0.4f * (float)t) * wv0;
      float pv = pl[0][t];
      p = act ? pv : 0.f;
    });
    if (lane <= MH0 - ML0)
      A[64 + ML0 + lane] = gA[ML0 + lane] + gB[ML0 + lane];
    WAVE_SYNC();
    LQ = 64 + ML0; HQ = 64 + MH0;

    for (int a = 1; a < 8; ++a) {
      float wv = __shfl(wreg, a);
      int ML = __shfl(mlA, a), MH = __shfl(mhA, a);
      int T = MH - ML;
      int W = (T + 4) & ~3;                // <= 56
      proj_scan(gA, gB, 51, lane, [&](int t, bool act, float& sup, float& p) {
        sup = (-10.0f + 0.4f * (float)t) * wv;
        float pv = pl[a][t];
        p = act ? pv : 0.f;
      });
      if (lane < W)     kvs[lane] = (lane <= T) ? (gA[ML + lane] + gB[ML + lane]) : 0.f;
      if (lane < W - 1) q[LQ - 1 - lane] = 0.f;
      if (lane < T)     q[HQ + 1 + lane] = 0.f;
      WAVE_SYNC();
      conv_pad2(q, qn, kvs, ML, W, T, LQ, HQ, lane, 64);
      WAVE_SYNC();
      LQ += ML; HQ += MH;
      float* t_ = q; q = qn; qn = t_;
    }
  }

  // ---- elu projection (chunked scan over claimed span) ----
  {
    int span = HQ - LQ + 1;
    int LQl = LQ;
    const float* qf = q;
    proj_scan(gA, gB, span, lane, [&](int t, bool act, float& sup, float& p) {
      int tg = (LQl - 64) + t;            // grid index in [0,400]
      float raw = (-80.0f + 0.4f * (float)tg) + b1v;
      sup = (raw > 0.f) ? raw : expm1f(raw);
      p = act ? qf[LQl + t] : 0.f;
    });
  }
  WAVE_SYNC();

  // ---- wf projection: x2 (in gA/gB) -> xw ----
  float x2v = (lane < 51) ? (gA[lane] + gB[lane]) : 0.f;
  WAVE_SYNC();                            // fence: read before re-zero
  int MLf, MHf;
  proj_bounds(wfv, MLf, MHf);
  proj_scan(gA, gB, 51, lane, [&](int t, bool act, float& sup, float& p) {
    sup = (-10.0f + 0.4f * (float)t) * wfv;
    p = act ? x2v : 0.f;
  });
  WAVE_SYNC();
  if (lane <= MHf - MLf)
    xw_ws[task * 51 + MLf + lane] = gA[MLf + lane] + gB[MLf + lane];
}

// ====== Kernel 3: TREE convolution — depth 5 ======
__global__ __launch_bounds__(256) void k_final(
    const float* __restrict__ xw_ws, const float* __restrict__ wf_ws,
    const float* __restrict__ v_ws,
    void* __restrict__ out, const int* __restrict__ flag)
{
  __shared__ __align__(16) float bufA[4608];
  __shared__ __align__(16) float bufB[4608];
  __shared__ int meta_s[63];
  __shared__ int meta_l[63];
  __shared__ int meta_ml[32];
  __shared__ int meta_g[6];
  __shared__ int meta_mltot;
  __shared__ float gA[53], gB[54];

  const int n    = blockIdx.x;
  const int tid  = threadIdx.x;
  const int lane = tid & 63;
  const int bf   = *flag;

  float wfreg = (lane < 32) ? wf_ws[n * 32 + lane] : 0.f;
  float vv    = v_ws[n];

  for (int i = tid; i < 4608; i += 256) { bufA[i] = 0.f; bufB[i] = 0.f; }

  if (tid < 64) {
    int ml, mh;
    proj_bounds(wfreg, ml, mh);
    if (lane < 32) meta_ml[lane] = ml;
    int msum = ml;
#pragma unroll
    for (int d = 1; d < 32; d <<= 1) msum += __shfl_xor(msum, d);
    if (lane == 0) meta_mltot = msum;

    int curlen = mh - ml + 1;
    int base = 0, Ncur = 32;
#pragma unroll
    for (int c = 0; c <= 5; ++c) {
      int lm = (lane < Ncur) ? curlen : 0;
#pragma unroll
      for (int d = 1; d < 32; d <<= 1) {
        int o = __shfl_xor(lm, d);
        lm = (o > lm) ? o : lm;
      }
      int G = (lm + 11) & ~3;
      int sp = ((curlen + 3) & ~3) + G;
      int inc = (lane < Ncur) ? sp : 0;
      int v0 = inc;
#pragma unroll
      for (int d = 1; d < 32; d <<= 1) {
        int u = __shfl_up(inc, d);
        if (lane >= d && lane < 32) inc += u;
      }
      if (lane < Ncur) {
        meta_s[base + lane] = 832 + (inc - v0);
        meta_l[base + lane] = curlen;
      }
      if (lane == 0) meta_g[c] = G;
      if (c < 5) {
        int l0 = __shfl(curlen, 2 * lane);
        int l1 = __shfl(curlen, 2 * lane + 1);
        curlen = l0 + l1 - 1;
        base += Ncur;
        Ncur >>= 1;
      }
    }
  }
  __syncthreads();

  {
    int g = tid >> 3, i = tid & 7;
    int s = meta_s[g], l = meta_l[g], ml = meta_ml[g];
    const float* row = xw_ws + (n * 32 + g) * 51 + ml;
    for (int i0 = i; i0 < l; i0 += 8) bufA[s + i0] = row[i0];
  }
  __syncthreads();

#pragma unroll
  for (int c = 1; c <= 5; ++c) {
    const float* bin = (c & 1) ? bufA : bufB;
    float*       bout = (c & 1) ? bufB : bufA;
    const int Nout = 32 >> c;
    const int lg = 3 + c;
    const int gs = 1 << lg;
    const int k  = tid >> lg;
    const int st = tid & (gs - 1);
    const int bc = 64 - (64 >> c);
    const int bp = 64 - (64 >> (c - 1));
    const int i0 = bp + 2 * k;
    const int sA = meta_s[i0];
    const int sB = meta_s[i0 + 1];
    const int lB = meta_l[i0 + 1];
    const int sO = meta_s[bc + k];
    const int lO = meta_l[bc + k];
    const int W  = (lB + 3) & ~3;

    for (int j = st * 2; j < lO; j += gs * 2) {
      const float* Ap = bin + sA + j + 1;
      float a0 = 0.f, a1 = 0.f;
      for (int m = 0; m < W; m += 4) {
        float4 k4 = *(const float4*)(bin + sB + m);
        float v0 = Ap[-m], v1 = Ap[-m - 1], v2 = Ap[-m - 2];
        float v3 = Ap[-m - 3], v4 = Ap[-m - 4];
        a0 = fmaf(k4.x, v1, fmaf(k4.y, v2, fmaf(k4.z, v3, fmaf(k4.w, v4, a0))));
        a1 = fmaf(k4.x, v0, fmaf(k4.y, v1, fmaf(k4.z, v2, fmaf(k4.w, v3, a1))));
      }
      bout[sO + j] = a0;
      if (j + 1 < lO) bout[sO + j + 1] = a1;
    }

    if (c >= 2 && c <= 4) {
      int G = meta_g[c];
      for (int p = tid; p < G; p += 256) bout[832 - G + p] = 0.f;
      for (int k2 = 0; k2 < Nout; ++k2) {
        int ss = meta_s[bc + k2] + meta_l[bc + k2];
        int ee = (k2 + 1 < Nout) ? meta_s[bc + k2 + 1]
                                 : ss + G + 3;
        for (int p = ss + tid; p < ee; p += 256) bout[p] = 0.f;
      }
    }
    __syncthreads();
  }

  if (tid < 64) {
    int s5 = meta_s[62], l5 = meta_l[62], mlt = meta_mltot;
    const float* qf = bufB + s5;
    proj_scan(gA, gB, l5, lane, [&](int t, bool act, float& sup, float& p) {
      int tg = mlt + t;
      sup = (-320.0f + 0.4f * (float)tg) + vv;
      p = act ? qf[t] : 0.f;
    });
    WAVE_SYNC();
    if (lane < 51) {
      float o = gA[lane] + gB[lane];
      if (bf) ((u16*)out)[n * 51 + lane] = f2bf(o);
      else    ((float*)out)[n * 51 + lane] = o;
    }
  }
}

// =========================== launcher ===========================
extern "C" void kernel_launch(void* const* d_in, const int* in_sizes, int n_in,
                              void* d_out, int out_size, void* d_ws, size_t ws_size,
                              hipStream_t stream)
{
  float* ws    = (float*)d_ws;
  float* w1_ws = ws;                       // 1024*256
  float* b1_ws = w1_ws + 1024 * 256;       // 1024*32
  float* wf_ws = b1_ws + 1024 * 32;        // 1024*32
  float* v_ws  = wf_ws + 1024 * 32;        // 1024
  float* xw_ws = v_ws  + 1024;             // 1024*32*51
  int*   flag  = (int*)(xw_ws + 1024 * 32 * 51);

  k_mlp<<<1024, 64, 0, stream>>>(d_in[1],
      d_in[2], d_in[3], d_in[4], d_in[5], d_in[6], d_in[7],
      d_in[8], d_in[9], d_in[10], d_in[11], d_in[12], d_in[13],
      d_in[14], d_in[15],
      w1_ws, b1_ws, wf_ws, v_ws, flag);

  k_perembed<<<16384, 128, 0, stream>>>(d_in[0], w1_ws, b1_ws, wf_ws, xw_ws, flag);

  k_final<<<1024, 256, 0, stream>>>(xw_ws, wf_ws, v_ws, d_out, flag);
}